// Round 1
// baseline (15496.962 us; speedup 1.0000x reference)
//
#include <hip/hip_runtime.h>
#include <math.h>

// LSTM: B=64, T=784, I=1, H=600. Persistent dataflow kernel.
#define BB 64
#define TT 784
#define HH 600
#define RG 50          // row-groups (cells split 600/12)
#define SGN 4          // batch-groups (64/16)
#define CPW 12         // cells per WG
#define BSUB 16        // batches per WG
#define NWG (RG*SGN)   // 200 workgroups, 1 per CU (LDS-forced)
#define BLOCK 768      // 12 waves: (kq:16)*(bg:4)*(c:12)
#define NBLK 150       // K dim in float4 units (600/4)
#define WSTRIDE 150    // W row stride (float4)
#define HSTRIDE 151    // h row stride (float4, +1 pad)
#define LDS_BYTES ((48*WSTRIDE + BSUB*HSTRIDE)*16)   // 153856 B

__device__ __forceinline__ float dot4acc(float4 a, float4 b, float acc) {
    acc = fmaf(a.x, b.x, acc);
    acc = fmaf(a.y, b.y, acc);
    acc = fmaf(a.z, b.z, acc);
    acc = fmaf(a.w, b.w, acc);
    return acc;
}

extern "C" __global__ void __launch_bounds__(BLOCK, 1)
lstm_main(const float* __restrict__ x, const float* __restrict__ hs0,
          const float* __restrict__ cs0, const float* __restrict__ W_ih,
          const float* __restrict__ W_hh, const float* __restrict__ b_ih,
          const float* __restrict__ b_hh, float* __restrict__ hbuf,
          unsigned int* __restrict__ flags)
{
    extern __shared__ float4 lds4[];
    float4* W4 = lds4;                  // [48 rows][150]
    float4* h4 = lds4 + 48 * WSTRIDE;   // [16 b][151]

    const int wg  = blockIdx.x;
    const int rg  = wg % RG;
    const int sg  = wg / RG;
    const int tid = threadIdx.x;
    const int kq  = tid & 15;          // k-split lane (bits 0-3 of lane)
    const int bg  = (tid >> 4) & 3;    // batch quad
    const int c   = tid >> 6;          // local cell 0..11 (one per wave)
    const int b0  = sg * BSUB;
    const int cell = rg * CPW + c;

    // ---- one-time: stage W_hh slice into LDS (rows g*600 + rg*12 + cl) ----
    for (int i = tid; i < 48 * WSTRIDE; i += BLOCK) {
        int rowl = i / WSTRIDE, col = i - rowl * WSTRIDE;
        int g = rowl / CPW, cl = rowl - g * CPW;
        int grow = g * HH + rg * CPW + cl;
        W4[i] = ((const float4*)(W_hh + (size_t)grow * HH))[col];
    }

    // per-thread constants for the pointwise phase (kq==0 threads own cells)
    float wih[4], bias[4], cst[4];
    if (kq == 0) {
        #pragma unroll
        for (int g = 0; g < 4; ++g) {
            int grow = g * HH + cell;
            wih[g]  = W_ih[grow];
            bias[g] = b_ih[grow] + b_hh[grow];
        }
        #pragma unroll
        for (int bi = 0; bi < 4; ++bi)
            cst[bi] = cs0[(size_t)(b0 + bg * 4 + bi) * HH + cell];
    }
    __syncthreads();

    unsigned int* myflag = &flags[(sg * RG + rg) * 16];

    for (int t = 0; t < TT; ++t) {
        // ---- wait for all 50 producers of our batch-group to finish t-1 ----
        if (t > 0) {
            if (tid < RG) {
                unsigned int* f = &flags[(sg * RG + tid) * 16];
                while (__hip_atomic_load(f, __ATOMIC_ACQUIRE,
                                         __HIP_MEMORY_SCOPE_AGENT) < (unsigned)t) {}
            }
            __syncthreads();
        }

        // ---- stage h slice [16][600] -> LDS (padded rows) ----
        const float* hsrc = (t == 0) ? hs0 : (hbuf + (size_t)(t & 1) * BB * HH);
        for (int i = tid; i < BSUB * WSTRIDE; i += BLOCK) {
            int row = i / WSTRIDE, col = i - row * WSTRIDE;
            h4[row * HSTRIDE + col] =
                ((const float4*)(hsrc + (size_t)(b0 + row) * HH))[col];
        }
        __syncthreads();

        // ---- GEMM: acc[g][bi] = sum_k W[g,cell,k] * h[b,k], k-split 16 ----
        float acc[4][4] = {};
        for (int blk = kq; blk < NBLK; blk += 16) {
            float4 hv0 = h4[(bg * 4 + 0) * HSTRIDE + blk];
            float4 hv1 = h4[(bg * 4 + 1) * HSTRIDE + blk];
            float4 hv2 = h4[(bg * 4 + 2) * HSTRIDE + blk];
            float4 hv3 = h4[(bg * 4 + 3) * HSTRIDE + blk];
            #pragma unroll
            for (int g = 0; g < 4; ++g) {
                float4 wv = W4[(g * CPW + c) * WSTRIDE + blk];
                acc[g][0] = dot4acc(wv, hv0, acc[g][0]);
                acc[g][1] = dot4acc(wv, hv1, acc[g][1]);
                acc[g][2] = dot4acc(wv, hv2, acc[g][2]);
                acc[g][3] = dot4acc(wv, hv3, acc[g][3]);
            }
        }

        // ---- reduce across the 16 kq lanes (lane bits 0-3) ----
        #pragma unroll
        for (int g = 0; g < 4; ++g)
            #pragma unroll
            for (int bi = 0; bi < 4; ++bi) {
                float v = acc[g][bi];
                v += __shfl_xor(v, 1);
                v += __shfl_xor(v, 2);
                v += __shfl_xor(v, 4);
                v += __shfl_xor(v, 8);
                acc[g][bi] = v;
            }

        // ---- pointwise LSTM cell update + write h_next ----
        float* hdst = hbuf + (size_t)((t + 1) & 1) * BB * HH;
        if (kq == 0) {
            #pragma unroll
            for (int bi = 0; bi < 4; ++bi) {
                int b = b0 + bg * 4 + bi;
                float xv = x[(size_t)b * TT + t];
                float gi = acc[0][bi] + xv * wih[0] + bias[0];
                float gf = acc[1][bi] + xv * wih[1] + bias[1];
                float gg = acc[2][bi] + xv * wih[2] + bias[2];
                float go = acc[3][bi] + xv * wih[3] + bias[3];
                float iv = 1.f / (1.f + expf(-gi));
                float fv = 1.f / (1.f + expf(-gf));
                float gv = tanhf(gg);
                float ov = 1.f / (1.f + expf(-go));
                float cn = fv * cst[bi] + iv * gv;
                cst[bi] = cn;
                hdst[(size_t)b * HH + cell] = ov * tanhf(cn);
            }
        }
        __syncthreads();   // all waves' h stores drained (vmcnt(0) before barrier)
        if (tid == 0) {
            __threadfence();                       // agent fence: L2 writeback
            __hip_atomic_store(myflag, (unsigned)(t + 1), __ATOMIC_RELEASE,
                               __HIP_MEMORY_SCOPE_AGENT);
        }
    }
}

// final projection: out[b,o] = h_T[b,:] @ W_out[o,:] + b_out[o]
extern "C" __global__ void lstm_out(const float* __restrict__ hbuf0,
                                    const float* __restrict__ W_out,
                                    const float* __restrict__ b_out,
                                    float* __restrict__ out)
{
    int b = blockIdx.x;
    int lane = threadIdx.x;
    float acc[10] = {};
    for (int k = lane; k < HH; k += 64) {
        float hv = hbuf0[(size_t)b * HH + k];
        #pragma unroll
        for (int o = 0; o < 10; ++o)
            acc[o] += hv * W_out[(size_t)o * HH + k];
    }
    #pragma unroll
    for (int o = 0; o < 10; ++o) {
        float v = acc[o];
        for (int off = 32; off > 0; off >>= 1) v += __shfl_down(v, off);
        if (lane == 0) out[b * 10 + o] = v + b_out[o];
    }
}

extern "C" void kernel_launch(void* const* d_in, const int* in_sizes, int n_in,
                              void* d_out, int out_size, void* d_ws, size_t ws_size,
                              hipStream_t stream)
{
    const float* x     = (const float*)d_in[0];
    const float* hs0   = (const float*)d_in[1];
    const float* cs0   = (const float*)d_in[2];
    const float* W_ih  = (const float*)d_in[3];
    const float* W_hh  = (const float*)d_in[4];
    const float* b_ih  = (const float*)d_in[5];
    const float* b_hh  = (const float*)d_in[6];
    const float* W_out = (const float*)d_in[7];
    const float* b_out = (const float*)d_in[8];
    float* out = (float*)d_out;

    // workspace: hbuf[2][64][600] f32, then flags[200] padded to 64B lines
    float* hbuf = (float*)d_ws;
    unsigned int* flags = (unsigned int*)((char*)d_ws + (size_t)2 * BB * HH * sizeof(float));

    hipFuncSetAttribute((const void*)lstm_main,
                        hipFuncAttributeMaxDynamicSharedMemorySize, LDS_BYTES);

    hipMemsetAsync(flags, 0, NWG * 16 * sizeof(unsigned int), stream);
    hipLaunchKernelGGL(lstm_main, dim3(NWG), dim3(BLOCK), LDS_BYTES, stream,
                       x, hs0, cs0, W_ih, W_hh, b_ih, b_hh, hbuf, flags);
    // t=783 writes hbuf[(784)&1] = hbuf[0]
    hipLaunchKernelGGL(lstm_out, dim3(BB), dim3(64), 0, stream,
                       hbuf, W_out, b_out, out);
}

// Round 2
// 7599.237 us; speedup vs baseline: 2.0393x; 2.0393x over previous
//
#include <hip/hip_runtime.h>
#include <math.h>

// LSTM: B=64, T=784, I=1, H=600. Persistent dataflow kernel, IF$-mediated exchange.
#define BB 64
#define TT 784
#define HH 600
#define RG 50          // row-groups (2400 gate-rows / 48 per WG)
#define SGN 4          // batch-groups (64/16)
#define CPW 12         // cells per WG
#define BSUB 16        // batches per WG
#define NWG (RG*SGN)   // 200 workgroups, 1 per CU (LDS-forced)
#define BLOCK 768      // 12 waves: (kq:16)*(bg:4)*(c:12)
#define NBLK 150       // K dim in float4 units (600/4)
#define WSTRIDE 150    // W row stride (float4)
#define HSTRIDE 151    // h row stride (float4, +1 pad)
#define LDS_BYTES ((48*WSTRIDE + BSUB*HSTRIDE)*16)   // 153856 B

__device__ __forceinline__ float dot4acc(float4 a, float4 b, float acc) {
    acc = fmaf(a.x, b.x, acc);
    acc = fmaf(a.y, b.y, acc);
    acc = fmaf(a.z, b.z, acc);
    acc = fmaf(a.w, b.w, acc);
    return acc;
}

// three pipelined cache-bypassing 16B loads (served from IF$, one latency)
__device__ __forceinline__ void ldg3_bypass(const float4* g0, const float4* g1,
                                            const float4* g2,
                                            float4& a, float4& b, float4& c) {
    asm volatile(
        "global_load_dwordx4 %0, %3, off sc0 sc1\n\t"
        "global_load_dwordx4 %1, %4, off sc0 sc1\n\t"
        "global_load_dwordx4 %2, %5, off sc0 sc1\n\t"
        "s_waitcnt vmcnt(0)"
        : "=&v"(a), "=&v"(b), "=&v"(c)
        : "v"(g0), "v"(g1), "v"(g2)
        : "memory");
}

__device__ __forceinline__ float4 ldg1_bypass(const float4* g) {
    float4 v;
    asm volatile(
        "global_load_dwordx4 %0, %1, off sc0 sc1\n\t"
        "s_waitcnt vmcnt(0)"
        : "=&v"(v) : "v"(g) : "memory");
    return v;
}

__device__ __forceinline__ void stg_bypass(float* p, float v) {
    asm volatile("global_store_dword %0, %1, off sc0 sc1"
                 :: "v"(p), "v"(v) : "memory");
}

__device__ __forceinline__ float sigm_f(float v) {
    return 1.f / (1.f + __expf(-v));
}
__device__ __forceinline__ float tanh_f(float v) {
    return 1.f - 2.f / (__expf(2.f * v) + 1.f);
}

extern "C" __global__ void __launch_bounds__(BLOCK, 1)
lstm_main(const float* __restrict__ x, const float* __restrict__ hs0,
          const float* __restrict__ cs0, const float* __restrict__ W_ih,
          const float* __restrict__ W_hh, const float* __restrict__ b_ih,
          const float* __restrict__ b_hh, float* __restrict__ hbuf,
          unsigned int* __restrict__ flags)
{
    extern __shared__ float4 lds4[];
    float4* W4 = lds4;                  // [48 rows][150]
    float4* h4 = lds4 + 48 * WSTRIDE;   // [16 b][151]

    const int wg  = blockIdx.x;
    const int rg  = wg % RG;
    const int sg  = wg / RG;
    const int tid = threadIdx.x;
    const int kq  = tid & 15;          // k-split lane (bits 0-3 of lane)
    const int bg  = (tid >> 4) & 3;    // batch quad
    const int c   = tid >> 6;          // local cell 0..11 (one per wave)
    const int b0  = sg * BSUB;
    const int cell = rg * CPW + c;

    // ---- one-time: stage W_hh slice into LDS (rows g*600 + rg*12 + cl) ----
    for (int i = tid; i < 48 * WSTRIDE; i += BLOCK) {
        int rowl = i / WSTRIDE, col = i - rowl * WSTRIDE;
        int g = rowl / CPW, cl = rowl - g * CPW;
        int grow = g * HH + rg * CPW + cl;
        W4[i] = ((const float4*)(W_hh + (size_t)grow * HH))[col];
    }

    // precomputed h-staging coordinates (3 guaranteed + 1 tail element)
    const int i0 = tid, i1 = tid + BLOCK, i2 = tid + 2 * BLOCK, i3 = 2304 + tid;
    const int r0 = i0 / WSTRIDE, c0 = i0 - r0 * WSTRIDE;
    const int r1 = i1 / WSTRIDE, c1 = i1 - r1 * WSTRIDE;
    const int r2 = i2 / WSTRIDE, c2 = i2 - r2 * WSTRIDE;
    const int r3 = i3 / WSTRIDE, c3 = i3 - r3 * WSTRIDE;
    const size_t so0 = (size_t)(b0 + r0) * NBLK + c0;   // in float4 units
    const size_t so1 = (size_t)(b0 + r1) * NBLK + c1;
    const size_t so2 = (size_t)(b0 + r2) * NBLK + c2;
    const size_t so3 = (size_t)(b0 + r3) * NBLK + c3;
    const int d0 = r0 * HSTRIDE + c0, d1 = r1 * HSTRIDE + c1;
    const int d2 = r2 * HSTRIDE + c2, d3 = r3 * HSTRIDE + c3;

    // per-thread constants for the pointwise phase (kq<4 lanes own (cell,batch))
    float wihv[4], biasv[4], cst = 0.f;
    const int myb = b0 + bg * 4 + kq;        // valid when kq<4
    if (kq < 4) {
        #pragma unroll
        for (int g = 0; g < 4; ++g) {
            int grow = g * HH + cell;
            wihv[g]  = W_ih[grow];
            biasv[g] = b_ih[grow] + b_hh[grow];
        }
        cst = cs0[(size_t)myb * HH + cell];
    }
    __syncthreads();

    unsigned int* myflag = &flags[(sg * RG + rg) * 16];

    for (int t = 0; t < TT; ++t) {
        // early x prefetch (cached read-only load; independent of the flags)
        float xv = 0.f;
        if (kq < 4) xv = x[(size_t)myb * TT + t];

        // ---- wait for all 50 producers of our batch-group to finish t-1 ----
        if (t > 0) {
            if (tid < RG) {
                const unsigned int* f = &flags[(sg * RG + tid) * 16];
                while (__hip_atomic_load(f, __ATOMIC_RELAXED,
                                         __HIP_MEMORY_SCOPE_AGENT) < (unsigned)t) {}
            }
            __syncthreads();
        }

        // ---- stage h slice [16][600] -> LDS via IF$-bypass loads ----
        const float4* hsrc = (t == 0) ? (const float4*)hs0
                                      : (const float4*)(hbuf + (size_t)(t & 1) * BB * HH);
        {
            float4 v0, v1, v2;
            ldg3_bypass(hsrc + so0, hsrc + so1, hsrc + so2, v0, v1, v2);
            h4[d0] = v0; h4[d1] = v1; h4[d2] = v2;
            if (tid < 96) h4[d3] = ldg1_bypass(hsrc + so3);
        }
        __syncthreads();

        // ---- GEMM: acc[g][bi] = sum_k W[g,cell,k] * h[b,k], k-split 16 ----
        float acc[4][4] = {};
        for (int blk = kq; blk < NBLK; blk += 16) {
            float4 hv0 = h4[(bg * 4 + 0) * HSTRIDE + blk];
            float4 hv1 = h4[(bg * 4 + 1) * HSTRIDE + blk];
            float4 hv2 = h4[(bg * 4 + 2) * HSTRIDE + blk];
            float4 hv3 = h4[(bg * 4 + 3) * HSTRIDE + blk];
            #pragma unroll
            for (int g = 0; g < 4; ++g) {
                float4 wv = W4[(g * CPW + c) * WSTRIDE + blk];
                acc[g][0] = dot4acc(wv, hv0, acc[g][0]);
                acc[g][1] = dot4acc(wv, hv1, acc[g][1]);
                acc[g][2] = dot4acc(wv, hv2, acc[g][2]);
                acc[g][3] = dot4acc(wv, hv3, acc[g][3]);
            }
        }

        // ---- butterfly reduce across the 16 kq lanes (all lanes get sums) ----
        #pragma unroll
        for (int g = 0; g < 4; ++g)
            #pragma unroll
            for (int bi = 0; bi < 4; ++bi) {
                float v = acc[g][bi];
                v += __shfl_xor(v, 1);
                v += __shfl_xor(v, 2);
                v += __shfl_xor(v, 4);
                v += __shfl_xor(v, 8);
                acc[g][bi] = v;
            }

        // ---- pointwise LSTM cell update + bypass-store h_next ----
        float* hdst = hbuf + (size_t)((t + 1) & 1) * BB * HH;
        if (kq < 4) {
            float gi = acc[0][kq] + xv * wihv[0] + biasv[0];
            float gf = acc[1][kq] + xv * wihv[1] + biasv[1];
            float gg = acc[2][kq] + xv * wihv[2] + biasv[2];
            float go = acc[3][kq] + xv * wihv[3] + biasv[3];
            float cn = sigm_f(gf) * cst + sigm_f(gi) * tanh_f(gg);
            cst = cn;
            stg_bypass(&hdst[(size_t)myb * HH + cell], sigm_f(go) * tanh_f(cn));
        }
        __syncthreads();   // vmcnt(0) drain: all waves' h stores are in IF$
        if (tid == 0)
            __hip_atomic_store(myflag, (unsigned)(t + 1), __ATOMIC_RELAXED,
                               __HIP_MEMORY_SCOPE_AGENT);
    }
}

// final projection: out[b,o] = h_T[b,:] @ W_out[o,:] + b_out[o]
extern "C" __global__ void lstm_out(const float* __restrict__ hbuf0,
                                    const float* __restrict__ W_out,
                                    const float* __restrict__ b_out,
                                    float* __restrict__ out)
{
    int b = blockIdx.x;
    int lane = threadIdx.x;
    float acc[10] = {};
    for (int k = lane; k < HH; k += 64) {
        float hv = hbuf0[(size_t)b * HH + k];
        #pragma unroll
        for (int o = 0; o < 10; ++o)
            acc[o] += hv * W_out[(size_t)o * HH + k];
    }
    #pragma unroll
    for (int o = 0; o < 10; ++o) {
        float v = acc[o];
        for (int off = 32; off > 0; off >>= 1) v += __shfl_down(v, off);
        if (lane == 0) out[b * 10 + o] = v + b_out[o];
    }
}

extern "C" void kernel_launch(void* const* d_in, const int* in_sizes, int n_in,
                              void* d_out, int out_size, void* d_ws, size_t ws_size,
                              hipStream_t stream)
{
    const float* x     = (const float*)d_in[0];
    const float* hs0   = (const float*)d_in[1];
    const float* cs0   = (const float*)d_in[2];
    const float* W_ih  = (const float*)d_in[3];
    const float* W_hh  = (const float*)d_in[4];
    const float* b_ih  = (const float*)d_in[5];
    const float* b_hh  = (const float*)d_in[6];
    const float* W_out = (const float*)d_in[7];
    const float* b_out = (const float*)d_in[8];
    float* out = (float*)d_out;

    // workspace: hbuf[2][64][600] f32, then flags[200] padded to 64B lines
    float* hbuf = (float*)d_ws;
    unsigned int* flags = (unsigned int*)((char*)d_ws + (size_t)2 * BB * HH * sizeof(float));

    hipFuncSetAttribute((const void*)lstm_main,
                        hipFuncAttributeMaxDynamicSharedMemorySize, LDS_BYTES);

    hipMemsetAsync(flags, 0, NWG * 16 * sizeof(unsigned int), stream);
    hipLaunchKernelGGL(lstm_main, dim3(NWG), dim3(BLOCK), LDS_BYTES, stream,
                       x, hs0, cs0, W_ih, W_hh, b_ih, b_hh, hbuf, flags);
    // t=783 writes hbuf[(784)&1] = hbuf[0]
    hipLaunchKernelGGL(lstm_out, dim3(BB), dim3(64), 0, stream,
                       hbuf, W_out, b_out, out);
}